// Round 2
// baseline (167.391 us; speedup 1.0000x reference)
//
#include <hip/hip_runtime.h>
#include <hip/hip_bf16.h>

// FocusAttention: B=8, L=S=1024, H=8, E=D=64
// A = softmax(c * s^2) rowwise, c = sqrt(sum s^2 / sum s^4) (full-row const
// -> two passes over K; recompute QK^T in pass 2). out = A @ v, fp32.
//
// R8: R7 counters: conflicts only fell 2.6M->2.1M -> wbuf wasn't the main
// source; the V-tile ds_read_b128 (64B n-stride -> 8-way bank alias) was.
// Fix: V never touches LDS. Next tile's V fragments (4x f16x8 = 16 VGPR)
// are prefetched DIRECT from global (same-XCD L2-resident) at the top of
// each iteration; the score->exp->permlane chain hides the ~200cy latency.
// Manual 2-deep ping-pong (named v_a/v_b, no runtime-indexed arrays).
//  - V-read bank conflicts gone (register operands)
//  - V glds staging gone -> barrier vmcnt drain waits on K only
//  - LDS 16KB -> 8KB
// Kept from R7: swapped-operand QK^T (S^T = mfma(K,Q)), in-register w->A-frag
// via cvt_pkrtz + permlane32/16_swap, per-lane scalar stats/denominator,
// fp16 operands, XCD swizzle, XOR chunk swizzle on K/Q, raw v_exp_f32.

#define B_ 8
#define L_ 1024
#define H_ 8
#define E_ 64
#define S_ 1024
#define D_ 64
#define BH_ 64

typedef _Float16 f16_t;
typedef _Float16 f16x8 __attribute__((ext_vector_type(8)));
typedef _Float16 f16x4v __attribute__((ext_vector_type(4)));
typedef float f32x4 __attribute__((ext_vector_type(4)));
typedef unsigned u32x4 __attribute__((ext_vector_type(4)));

#define MFMA16F(a, b, c) __builtin_amdgcn_mfma_f32_16x16x32_f16(a, b, c, 0, 0, 0)
#define GLDS16(g, l)                                                        \
  __builtin_amdgcn_global_load_lds(                                         \
      (const __attribute__((address_space(1))) void*)(g),                   \
      (__attribute__((address_space(3))) void*)(l), 16, 0, 0)

#if __has_builtin(__builtin_amdgcn_exp2f)
#define EXP2(x) __builtin_amdgcn_exp2f(x)
#else
#define EXP2(x) exp2f(x)
#endif

// pack 2 f32 -> 1 dword of 2 f16 (v_cvt_pkrtz_f16_f32)
static __device__ __forceinline__ unsigned pkh(float a, float b) {
  return __builtin_bit_cast(unsigned, __builtin_amdgcn_cvt_pkrtz(a, b));
}

// v_permlane32_swap_b32: x[32:63] <-> y[0:31].
// In 16-lane group vectors: x=[X0,X1,X2,X3], y=[Y0..Y3] ->
//   x'=[X0,X1,Y0,Y1], y'=[X2,X3,Y2,Y3]
static __device__ __forceinline__ void pl32_swap(unsigned& x, unsigned& y) {
#if __has_builtin(__builtin_amdgcn_permlane32_swap)
  auto r = __builtin_amdgcn_permlane32_swap(x, y, false, false);
  x = r[0];
  y = r[1];
#else
  unsigned xs = __shfl_xor((int)x, 32, 64), ys = __shfl_xor((int)y, 32, 64);
  bool hi = (threadIdx.x & 32) != 0;
  unsigned nx = hi ? ys : x;
  unsigned ny = hi ? y : xs;
  x = nx;
  y = ny;
#endif
}

// v_permlane16_swap_b32: x rows {1,3} <-> y rows {0,2} (16-lane rows).
//   x=[A0,A1,A2,A3], y=[B0..B3] -> x'=[A0,B0,A2,B2], y'=[A1,B1,A3,B3]
static __device__ __forceinline__ void pl16_swap(unsigned& x, unsigned& y) {
#if __has_builtin(__builtin_amdgcn_permlane16_swap)
  auto r = __builtin_amdgcn_permlane16_swap(x, y, false, false);
  x = r[0];
  y = r[1];
#else
  unsigned xs = __shfl_xor((int)x, 16, 64), ys = __shfl_xor((int)y, 16, 64);
  bool odd = (threadIdx.x & 16) != 0;
  unsigned nx = odd ? ys : x;
  unsigned ny = odd ? y : xs;
  x = nx;
  y = ny;
#endif
}

// ---------------------------------------------------------------------------
// prep: blocks [0,8192) = phi_p on q,k rows (4 rows/wave, float4 loads,
// f16x4 swizzled stores); blocks [8192,10240) = V transpose to
// vt[bh][st=S/32][64 d][32 s] f16 (linear).
// XOR chunk swizzle (q/k only): chunk c of row l stored at chunk c^(l&7).
// ---------------------------------------------------------------------------
__global__ __launch_bounds__(256) void prep_kernel(
    const float* __restrict__ q, const float* __restrict__ k,
    const float* __restrict__ v, f16_t* __restrict__ qf,
    f16_t* __restrict__ kf, f16_t* __restrict__ vt) {
  __shared__ float tile[32][68];
  int bid = blockIdx.x;
  if (bid < 8192) {
    int row = bid * 16 + (threadIdx.x >> 4);
    int p = threadIdx.x & 15;
    const float* src;
    f16_t* dst;
    int r = row;
    if (r < B_ * L_ * H_) { src = q; dst = qf; }
    else { r -= B_ * L_ * H_; src = k; dst = kf; }
    int b = r >> 13;            // r / (L*H)
    int l = (r >> 3) & 1023;
    int h = r & 7;
    float4 x = ((const float4*)(src + (size_t)r * 64))[p];
    float s0 = fmaxf(x.x, 0.f) * fmaxf(x.x, 0.f);
    float s1 = fmaxf(x.y, 0.f) * fmaxf(x.y, 0.f);
    float s2 = fmaxf(x.z, 0.f) * fmaxf(x.z, 0.f);
    float s3 = fmaxf(x.w, 0.f) * fmaxf(x.w, 0.f);
    float sum2 = (s0 + s1) + (s2 + s3);
    float sum4 = fmaf(s0, s0, s1 * s1) + fmaf(s2, s2, s3 * s3);
#pragma unroll
    for (int off = 1; off < 16; off <<= 1) {
      sum2 += __shfl_xor(sum2, off, 64);
      sum4 += __shfl_xor(sum4, off, 64);
    }
    float sc = (sum4 > 0.f) ? sqrtf(sum2 / sum4) : 0.f;
    f16x4v o = {(f16_t)(sc * s0), (f16_t)(sc * s1), (f16_t)(sc * s2),
                (f16_t)(sc * s3)};
    int c = p >> 1, e = (p & 1) * 4;
    int col = (((c ^ (l & 7)) << 3) | e);
    *(f16x4v*)(dst + ((size_t)(b * H_ + h) * 1024 + l) * 64 + col) = o;
  } else {
    int vb = bid - 8192;
    int bh = vb >> 5;
    int st = vb & 31;
    int b = bh >> 3, h = bh & 7;
    int t = threadIdx.x;
    int sl = t >> 3, dp = t & 7;
    const float* src =
        v + (((size_t)(b * S_ + st * 32 + sl) * H_ + h) * D_) + dp * 8;
    float4 f0 = ((const float4*)src)[0];
    float4 f1 = ((const float4*)src)[1];
    *(float4*)&tile[sl][dp * 8] = f0;
    *(float4*)&tile[sl][dp * 8 + 4] = f1;
    __syncthreads();
    int d = t >> 2, sc = t & 3;
    f16_t tmp[8];
#pragma unroll
    for (int j = 0; j < 8; ++j) tmp[j] = (f16_t)tile[sc * 8 + j][d];
    f16_t* dst = vt + (((size_t)bh * 32 + st) * 64 + d) * 32 + sc * 8;
    *(uint4*)dst = *(const uint4*)tmp;
  }
}

// ---------------------------------------------------------------------------
// K2: fused two-pass attention. Block = (b,h) x 64 q-rows; 4 waves x 16 rows.
// SWAPPED score MFMA: S^T = mfma(K_frag, Q_frag); lane(g,n) holds scores for
// q-row n at s={4g+r, 16+4g+r}. Row stats / denominator are per-lane scalars.
// PV A-frag w[q=n][s=8g..8g+7] assembled in-register via cvt_pkrtz +
// permlane32_swap + permlane16_swap (no LDS round-trip).
// Pass 1: barrier-free, K B-frags direct from global (L2-resident).
// Pass 2: K via glds double-buffer (1 barrier/tile); V via 2-deep register
// ping-pong prefetch direct from global (never in LDS).
// ---------------------------------------------------------------------------
__global__ __launch_bounds__(256, 4) void attn_kernel(
    const f16_t* __restrict__ qf, const f16_t* __restrict__ kf,
    const f16_t* __restrict__ vt, float* __restrict__ out) {
  __shared__ __align__(16) f16_t k_t[2][2048];   // 32 s-rows x 64 e (swizzled)

  int bh = blockIdx.x & 63;   // XCD swizzle: all q-blocks of a head co-located
  int qb = blockIdx.x >> 6;
  int b = bh >> 3, h = bh & 7;
  int tid = threadIdx.x;
  int wave = tid >> 6, lane = tid & 63;
  int g = lane >> 4, n = lane & 15;

  const f16_t* qf_b = qf + ((size_t)bh * L_ + qb * 64) * 64;
  const f16_t* kf_b = kf + (size_t)bh * S_ * 64;
  const f16_t* vt_b = vt + (size_t)bh * 32 * 2048;

  // Q fragments (swizzled chunk addressing); e-chunk g and g^4 (^32 elems)
  int arow = wave * 16 + n;
  int qoff = arow * 64 + ((g ^ (n & 7)) << 3);
  f16x8 qa0 = *(const f16x8*)(qf_b + qoff);
  f16x8 qa1 = *(const f16x8*)(qf_b + (qoff ^ 32));

  // K fragment offset in a tile (row n; row n+16 at +1024); same swizzle
  int koff = n * 64 + ((g ^ (n & 7)) << 3);
  int lds_o = tid * 8;  // lane-linear glds staging slot (16B/thread)

  const f32x4 fzero = {0.f, 0.f, 0.f, 0.f};
  f32x4 acc2 = fzero, acc4 = fzero, mx = fzero;

  // ---- PASS 1: row stats, barrier-free (K direct from global/L2) ----
  const f16_t* kg = kf_b;
#pragma unroll 2
  for (int t = 0; t < 32; ++t) {
    f16x8 b00 = *(const f16x8*)(kg + koff);
    f16x8 b01 = *(const f16x8*)(kg + (koff ^ 32));
    f16x8 b10 = *(const f16x8*)(kg + koff + 1024);
    f16x8 b11 = *(const f16x8*)(kg + (koff ^ 32) + 1024);
    kg += 2048;
    f32x4 sc0 = MFMA16F(b00, qa0, fzero);   // S^T[s=4g+r][q=n]
    sc0 = MFMA16F(b01, qa1, sc0);
    f32x4 sc1 = MFMA16F(b10, qa0, fzero);   // S^T[s=16+4g+r][q=n]
    sc1 = MFMA16F(b11, qa1, sc1);
    f32x4 t0 = sc0 * sc0, t1 = sc1 * sc1;   // v_pk_mul_f32
    acc2 += t0 + t1;                        // v_pk_add_f32
    acc4 += t0 * t0;                        // v_pk_fma_f32 (contracted)
    acc4 += t1 * t1;
    mx = __builtin_elementwise_max(mx, __builtin_elementwise_max(t0, t1));
  }
  // per-lane horizontal, then cross-group (all lanes with same n share a row)
  float a2 = (acc2[0] + acc2[1]) + (acc2[2] + acc2[3]);
  float a4 = (acc4[0] + acc4[1]) + (acc4[2] + acc4[3]);
  float m2 = fmaxf(fmaxf(mx[0], mx[1]), fmaxf(mx[2], mx[3]));
  a2 += __shfl_xor(a2, 16, 64);
  a4 += __shfl_xor(a4, 16, 64);
  m2 = fmaxf(m2, __shfl_xor(m2, 16, 64));
  a2 += __shfl_xor(a2, 32, 64);
  a4 += __shfl_xor(a4, 32, 64);
  m2 = fmaxf(m2, __shfl_xor(m2, 32, 64));
  const float LOG2E = 1.44269504f;
  float c2 = (a4 > 0.f) ? (sqrtf(a2 / a4) * LOG2E) : 0.f;  // scalar per lane
  float cm2 = c2 * m2;

  // ---- PASS 2: K glds double-buffer; V 2-deep register ping-pong ----
  f32x4 pv[4];
#pragma unroll
  for (int dg = 0; dg < 4; ++dg) pv[dg] = fzero;
  f32x4 denv = fzero;

  const f16_t* vt_g = vt_b + n * 32 + g * 8;  // per-lane V frag base
  f16x8 v_a0, v_a1, v_a2, v_a3, v_b0, v_b1, v_b2, v_b3;

  GLDS16(kf_b + lds_o, &k_t[0][lds_o]);
  v_a0 = *(const f16x8*)(vt_g + 0 * 512);   // tile 0 V frags -> regs
  v_a1 = *(const f16x8*)(vt_g + 1 * 512);
  v_a2 = *(const f16x8*)(vt_g + 2 * 512);
  v_a3 = *(const f16x8*)(vt_g + 3 * 512);

#define PASS2_BODY(T, VU0, VU1, VU2, VU3, VP0, VP1, VP2, VP3)               \
  {                                                                         \
    __syncthreads(); /* drains K glds -> tile (T) ready */                  \
    if ((T) < 31) {                                                         \
      int go = ((T) + 1) * 2048;                                            \
      GLDS16(kf_b + go + lds_o, &k_t[((T) + 1) & 1][lds_o]);                \
      const f16_t* vp = vt_g + go;                                          \
      VP0 = *(const f16x8*)(vp + 0 * 512); /* L2 latency hidden by chain */ \
      VP1 = *(const f16x8*)(vp + 1 * 512);                                  \
      VP2 = *(const f16x8*)(vp + 2 * 512);                                  \
      VP3 = *(const f16x8*)(vp + 3 * 512);                                  \
    }                                                                       \
    const f16_t* kt = k_t[(T) & 1];                                         \
    f16x8 b00 = *(const f16x8*)(kt + koff);                                 \
    f16x8 b01 = *(const f16x8*)(kt + (koff ^ 32));                          \
    f16x8 b10 = *(const f16x8*)(kt + koff + 1024);                          \
    f16x8 b11 = *(const f16x8*)(kt + (koff ^ 32) + 1024);                   \
    f32x4 sc0 = MFMA16F(b00, qa0, fzero);                                   \
    sc0 = MFMA16F(b01, qa1, sc0);                                           \
    f32x4 sc1 = MFMA16F(b10, qa0, fzero);                                   \
    sc1 = MFMA16F(b11, qa1, sc1);                                           \
    f32x4 e0 = sc0 * sc0 * c2 - cm2;                                        \
    f32x4 e1 = sc1 * sc1 * c2 - cm2;                                        \
    f32x4 w0, w1;                                                           \
    _Pragma("unroll") for (int r = 0; r < 4; ++r) {                         \
      w0[r] = EXP2(e0[r]);                                                  \
      w1[r] = EXP2(e1[r]);                                                  \
    }                                                                       \
    denv += w0 + w1;                                                        \
    unsigned X0 = pkh(w0[0], w0[1]), X1 = pkh(w0[2], w0[3]);                \
    unsigned Y0 = pkh(w1[0], w1[1]), Y1 = pkh(w1[2], w1[3]);                \
    pl32_swap(X0, Y0);                                                      \
    pl16_swap(X0, Y0);                                                      \
    pl32_swap(X1, Y1);                                                      \
    pl16_swap(X1, Y1);                                                      \
    u32x4 fu = {X0, X1, Y0, Y1};                                            \
    f16x8 wa = __builtin_bit_cast(f16x8, fu); /* w[q=n][s=8g..8g+7] */      \
    pv[0] = MFMA16F(wa, VU0, pv[0]);                                        \
    pv[1] = MFMA16F(wa, VU1, pv[1]);                                        \
    pv[2] = MFMA16F(wa, VU2, pv[2]);                                        \
    pv[3] = MFMA16F(wa, VU3, pv[3]);                                        \
  }

  for (int t = 0; t < 32; t += 2) {
    PASS2_BODY(t, v_a0, v_a1, v_a2, v_a3, v_b0, v_b1, v_b2, v_b3);
    PASS2_BODY(t + 1, v_b0, v_b1, v_b2, v_b3, v_a0, v_a1, v_a2, v_a3);
  }
#undef PASS2_BODY

  // denominator: per-lane scalar -> cross-group reduce -> shfl to rows
  float den = (denv[0] + denv[1]) + (denv[2] + denv[3]);
  den += __shfl_xor(den, 16, 64);
  den += __shfl_xor(den, 32, 64);  // den for q-row n, replicated over g
#pragma unroll
  for (int r = 0; r < 4; ++r) {
    float dr = __shfl(den, g * 4 + r, 64);  // den for q-row g*4+r
    float inv = 1.f / dr;
    int l = qb * 64 + wave * 16 + g * 4 + r;
    float* op = out + (((size_t)b * L_ + l) * H_ + h) * D_;
#pragma unroll
    for (int dg = 0; dg < 4; ++dg) op[dg * 16 + n] = pv[dg][r] * inv;
  }
}

extern "C" void kernel_launch(void* const* d_in, const int* in_sizes, int n_in,
                              void* d_out, int out_size, void* d_ws, size_t ws_size,
                              hipStream_t stream) {
  const float* q = (const float*)d_in[0];
  const float* k = (const float*)d_in[1];
  const float* v = (const float*)d_in[2];
  // d_in[3] (attn_mask) is all-False -> unused
  float* out = (float*)d_out;

  const size_t NE = (size_t)B_ * L_ * H_ * E_;  // 4,194,304 elems
  f16_t* qf = (f16_t*)d_ws;                     // ws usage: 3*NE*2B = 24 MB
  f16_t* kf = qf + NE;
  f16_t* vt = kf + NE;

  prep_kernel<<<8192 + 2048, 256, 0, stream>>>(q, k, v, qf, kf, vt);
  attn_kernel<<<BH_ * (L_ / 64), 256, 0, stream>>>(qf, kf, vt, out);
}

// Round 3
// 154.987 us; speedup vs baseline: 1.0800x; 1.0800x over previous
//
#include <hip/hip_runtime.h>
#include <hip/hip_bf16.h>

// FocusAttention: B=8, L=S=1024, H=8, E=D=64
// A = softmax(c * s^2) rowwise, c = sqrt(sum s^2 / sum s^4) (full-row const
// -> two passes over K; recompute QK^T in pass 2). out = A @ v, fp32.
//
// R9: R8 regression was diagnostic: conflicts 2.1M->0 yet +9us -> LDS
// conflicts were free; the +384MB of private per-wave V reads from L2 cost
// the 9us => L2-BW-bound (~4.3 TB/s/XCD). R7 traffic audit: pass1 K direct
// per-wave = 512MB + pass2 K 128MB + V 128MB = 768MB (~22us L2 floor).
// Fix: minimize L2 traffic.
//  - pass 1 K staged via the same glds double-buffer (shared by 4 waves):
//    512 -> 128 MB
//  - 128 q-rows/block (each wave = two 16-row sets, grid 512): per-block
//    K/V re-read amortized 2x more: total 768 -> 192 MB (~5.6us/XCD floor).
//    Second set doubles per-wave ILP to offset 4->2 blocks/CU occupancy.
// Kept from R7: swapped-operand QK^T (S^T = mfma(K,Q)), in-register w->A-frag
// via cvt_pkrtz + permlane32/16_swap, per-lane scalar stats/denominator,
// fp16 operands, XCD swizzle, XOR chunk swizzle on K/Q, glds double-buffer,
// raw v_exp_f32, V in LDS (R8: direct-global V regressed).

#define B_ 8
#define L_ 1024
#define H_ 8
#define E_ 64
#define S_ 1024
#define D_ 64
#define BH_ 64

typedef _Float16 f16_t;
typedef _Float16 f16x8 __attribute__((ext_vector_type(8)));
typedef _Float16 f16x4v __attribute__((ext_vector_type(4)));
typedef float f32x4 __attribute__((ext_vector_type(4)));
typedef unsigned u32x4 __attribute__((ext_vector_type(4)));

#define MFMA16F(a, b, c) __builtin_amdgcn_mfma_f32_16x16x32_f16(a, b, c, 0, 0, 0)
#define GLDS16(g, l)                                                        \
  __builtin_amdgcn_global_load_lds(                                         \
      (const __attribute__((address_space(1))) void*)(g),                   \
      (__attribute__((address_space(3))) void*)(l), 16, 0, 0)

#if __has_builtin(__builtin_amdgcn_exp2f)
#define EXP2(x) __builtin_amdgcn_exp2f(x)
#else
#define EXP2(x) exp2f(x)
#endif

// pack 2 f32 -> 1 dword of 2 f16 (v_cvt_pkrtz_f16_f32)
static __device__ __forceinline__ unsigned pkh(float a, float b) {
  return __builtin_bit_cast(unsigned, __builtin_amdgcn_cvt_pkrtz(a, b));
}

// v_permlane32_swap_b32: x[32:63] <-> y[0:31].
// In 16-lane group vectors: x=[X0,X1,X2,X3], y=[Y0..Y3] ->
//   x'=[X0,X1,Y0,Y1], y'=[X2,X3,Y2,Y3]
static __device__ __forceinline__ void pl32_swap(unsigned& x, unsigned& y) {
#if __has_builtin(__builtin_amdgcn_permlane32_swap)
  auto r = __builtin_amdgcn_permlane32_swap(x, y, false, false);
  x = r[0];
  y = r[1];
#else
  unsigned xs = __shfl_xor((int)x, 32, 64), ys = __shfl_xor((int)y, 32, 64);
  bool hi = (threadIdx.x & 32) != 0;
  unsigned nx = hi ? ys : x;
  unsigned ny = hi ? y : xs;
  x = nx;
  y = ny;
#endif
}

// v_permlane16_swap_b32: x rows {1,3} <-> y rows {0,2} (16-lane rows).
//   x=[A0,A1,A2,A3], y=[B0..B3] -> x'=[A0,B0,A2,B2], y'=[A1,B1,A3,B3]
static __device__ __forceinline__ void pl16_swap(unsigned& x, unsigned& y) {
#if __has_builtin(__builtin_amdgcn_permlane16_swap)
  auto r = __builtin_amdgcn_permlane16_swap(x, y, false, false);
  x = r[0];
  y = r[1];
#else
  unsigned xs = __shfl_xor((int)x, 16, 64), ys = __shfl_xor((int)y, 16, 64);
  bool odd = (threadIdx.x & 16) != 0;
  unsigned nx = odd ? ys : x;
  unsigned ny = odd ? y : xs;
  x = nx;
  y = ny;
#endif
}

// ---------------------------------------------------------------------------
// prep: blocks [0,8192) = phi_p on q,k rows (4 rows/wave, float4 loads,
// f16x4 swizzled stores); blocks [8192,10240) = V transpose to
// vt[bh][st=S/32][64 d][32 s] f16 (linear).
// XOR chunk swizzle (q/k only): chunk c of row l stored at chunk c^(l&7).
// ---------------------------------------------------------------------------
__global__ __launch_bounds__(256) void prep_kernel(
    const float* __restrict__ q, const float* __restrict__ k,
    const float* __restrict__ v, f16_t* __restrict__ qf,
    f16_t* __restrict__ kf, f16_t* __restrict__ vt) {
  __shared__ float tile[32][68];
  int bid = blockIdx.x;
  if (bid < 8192) {
    int row = bid * 16 + (threadIdx.x >> 4);
    int p = threadIdx.x & 15;
    const float* src;
    f16_t* dst;
    int r = row;
    if (r < B_ * L_ * H_) { src = q; dst = qf; }
    else { r -= B_ * L_ * H_; src = k; dst = kf; }
    int b = r >> 13;            // r / (L*H)
    int l = (r >> 3) & 1023;
    int h = r & 7;
    float4 x = ((const float4*)(src + (size_t)r * 64))[p];
    float s0 = fmaxf(x.x, 0.f) * fmaxf(x.x, 0.f);
    float s1 = fmaxf(x.y, 0.f) * fmaxf(x.y, 0.f);
    float s2 = fmaxf(x.z, 0.f) * fmaxf(x.z, 0.f);
    float s3 = fmaxf(x.w, 0.f) * fmaxf(x.w, 0.f);
    float sum2 = (s0 + s1) + (s2 + s3);
    float sum4 = fmaf(s0, s0, s1 * s1) + fmaf(s2, s2, s3 * s3);
#pragma unroll
    for (int off = 1; off < 16; off <<= 1) {
      sum2 += __shfl_xor(sum2, off, 64);
      sum4 += __shfl_xor(sum4, off, 64);
    }
    float sc = (sum4 > 0.f) ? sqrtf(sum2 / sum4) : 0.f;
    f16x4v o = {(f16_t)(sc * s0), (f16_t)(sc * s1), (f16_t)(sc * s2),
                (f16_t)(sc * s3)};
    int c = p >> 1, e = (p & 1) * 4;
    int col = (((c ^ (l & 7)) << 3) | e);
    *(f16x4v*)(dst + ((size_t)(b * H_ + h) * 1024 + l) * 64 + col) = o;
  } else {
    int vb = bid - 8192;
    int bh = vb >> 5;
    int st = vb & 31;
    int b = bh >> 3, h = bh & 7;
    int t = threadIdx.x;
    int sl = t >> 3, dp = t & 7;
    const float* src =
        v + (((size_t)(b * S_ + st * 32 + sl) * H_ + h) * D_) + dp * 8;
    float4 f0 = ((const float4*)src)[0];
    float4 f1 = ((const float4*)src)[1];
    *(float4*)&tile[sl][dp * 8] = f0;
    *(float4*)&tile[sl][dp * 8 + 4] = f1;
    __syncthreads();
    int d = t >> 2, sc = t & 3;
    f16_t tmp[8];
#pragma unroll
    for (int j = 0; j < 8; ++j) tmp[j] = (f16_t)tile[sc * 8 + j][d];
    f16_t* dst = vt + (((size_t)bh * 32 + st) * 64 + d) * 32 + sc * 8;
    *(uint4*)dst = *(const uint4*)tmp;
  }
}

// ---------------------------------------------------------------------------
// K2: fused two-pass attention. Block = (b,h) x 128 q-rows; 4 waves, each
// wave owns TWO 16-row sets (rows wave*32+[0,16) and +16).
// SWAPPED score MFMA: S^T = mfma(K_frag, Q_frag); lane(g,n) holds scores for
// q-row n at s={4g+r, 16+4g+r}. Row stats / denominator are per-lane scalars.
// PV A-frag w[q=n][s=8g..8g+7] assembled in-register via cvt_pkrtz +
// permlane32_swap + permlane16_swap (no LDS round-trip).
// BOTH passes stage K (and V in pass 2) via glds double-buffer shared by all
// 4 waves -> L2 traffic 192 MB total (vs 768 MB in R7).
// ---------------------------------------------------------------------------
__global__ __launch_bounds__(256, 2) void attn_kernel(
    const f16_t* __restrict__ qf, const f16_t* __restrict__ kf,
    const f16_t* __restrict__ vt, float* __restrict__ out) {
  __shared__ __align__(16) f16_t k_t[2][2048];   // 32 s-rows x 64 e (swizzled)
  __shared__ __align__(16) f16_t v_t[2][2048];   // 64 d-rows x 32 s (linear)

  int bh = blockIdx.x & 63;   // XCD swizzle: all q-blocks of a head co-located
  int qb = blockIdx.x >> 6;   // 0..7 (128 rows each)
  int b = bh >> 3, h = bh & 7;
  int tid = threadIdx.x;
  int wave = tid >> 6, lane = tid & 63;
  int g = lane >> 4, n = lane & 15;

  const f16_t* qf_b = qf + ((size_t)bh * L_ + qb * 128) * 64;
  const f16_t* kf_b = kf + (size_t)bh * S_ * 64;
  const f16_t* vt_b = vt + (size_t)bh * 32 * 2048;

  // Q fragments, two sets (swizzled chunk addressing)
  int arow = wave * 32 + n;
  int qoff0 = arow * 64 + ((g ^ (n & 7)) << 3);
  int qoff1 = qoff0 + 16 * 64;
  f16x8 qa0_0 = *(const f16x8*)(qf_b + qoff0);
  f16x8 qa1_0 = *(const f16x8*)(qf_b + (qoff0 ^ 32));
  f16x8 qa0_1 = *(const f16x8*)(qf_b + qoff1);
  f16x8 qa1_1 = *(const f16x8*)(qf_b + (qoff1 ^ 32));

  // K fragment offset in a tile (row n; row n+16 at +1024); same swizzle
  int koff = n * 64 + ((g ^ (n & 7)) << 3);
  int lds_o = tid * 8;  // lane-linear glds staging slot (16B/thread)

  const f32x4 fzero = {0.f, 0.f, 0.f, 0.f};
  f32x4 acc2_0 = fzero, acc4_0 = fzero, mx_0 = fzero;
  f32x4 acc2_1 = fzero, acc4_1 = fzero, mx_1 = fzero;

  // ---- PASS 1: row stats; K staged via glds double-buffer (shared) ----
  GLDS16(kf_b + lds_o, &k_t[0][lds_o]);
  for (int t = 0; t < 32; ++t) {
    __syncthreads();  // drains glds -> tile t ready
    if (t < 31)
      GLDS16(kf_b + (t + 1) * 2048 + lds_o, &k_t[(t + 1) & 1][lds_o]);
    const f16_t* kt = k_t[t & 1];
    f16x8 b00 = *(const f16x8*)(kt + koff);
    f16x8 b01 = *(const f16x8*)(kt + (koff ^ 32));
    f16x8 b10 = *(const f16x8*)(kt + koff + 1024);
    f16x8 b11 = *(const f16x8*)(kt + (koff ^ 32) + 1024);
    f32x4 sc0_0 = MFMA16F(b00, qa0_0, fzero);   // set0: S^T[s=4g+r][q=n]
    sc0_0 = MFMA16F(b01, qa1_0, sc0_0);
    f32x4 sc1_0 = MFMA16F(b10, qa0_0, fzero);
    sc1_0 = MFMA16F(b11, qa1_0, sc1_0);
    f32x4 sc0_1 = MFMA16F(b00, qa0_1, fzero);   // set1: rows +16
    sc0_1 = MFMA16F(b01, qa1_1, sc0_1);
    f32x4 sc1_1 = MFMA16F(b10, qa0_1, fzero);
    sc1_1 = MFMA16F(b11, qa1_1, sc1_1);
    f32x4 t0 = sc0_0 * sc0_0, t1 = sc1_0 * sc1_0;
    acc2_0 += t0 + t1;
    acc4_0 += t0 * t0;
    acc4_0 += t1 * t1;
    mx_0 = __builtin_elementwise_max(mx_0, __builtin_elementwise_max(t0, t1));
    f32x4 u0 = sc0_1 * sc0_1, u1 = sc1_1 * sc1_1;
    acc2_1 += u0 + u1;
    acc4_1 += u0 * u0;
    acc4_1 += u1 * u1;
    mx_1 = __builtin_elementwise_max(mx_1, __builtin_elementwise_max(u0, u1));
  }
  // kick off pass-2 tile 0 staging; stats reduce overlaps the load latency
  GLDS16(kf_b + lds_o, &k_t[0][lds_o]);
  GLDS16(vt_b + lds_o, &v_t[0][lds_o]);

  const float LOG2E = 1.44269504f;
  float c2_0, cm2_0, c2_1, cm2_1;
  {
    float a2 = (acc2_0[0] + acc2_0[1]) + (acc2_0[2] + acc2_0[3]);
    float a4 = (acc4_0[0] + acc4_0[1]) + (acc4_0[2] + acc4_0[3]);
    float m2 = fmaxf(fmaxf(mx_0[0], mx_0[1]), fmaxf(mx_0[2], mx_0[3]));
    a2 += __shfl_xor(a2, 16, 64);
    a4 += __shfl_xor(a4, 16, 64);
    m2 = fmaxf(m2, __shfl_xor(m2, 16, 64));
    a2 += __shfl_xor(a2, 32, 64);
    a4 += __shfl_xor(a4, 32, 64);
    m2 = fmaxf(m2, __shfl_xor(m2, 32, 64));
    c2_0 = (a4 > 0.f) ? (sqrtf(a2 / a4) * LOG2E) : 0.f;
    cm2_0 = c2_0 * m2;
  }
  {
    float a2 = (acc2_1[0] + acc2_1[1]) + (acc2_1[2] + acc2_1[3]);
    float a4 = (acc4_1[0] + acc4_1[1]) + (acc4_1[2] + acc4_1[3]);
    float m2 = fmaxf(fmaxf(mx_1[0], mx_1[1]), fmaxf(mx_1[2], mx_1[3]));
    a2 += __shfl_xor(a2, 16, 64);
    a4 += __shfl_xor(a4, 16, 64);
    m2 = fmaxf(m2, __shfl_xor(m2, 16, 64));
    a2 += __shfl_xor(a2, 32, 64);
    a4 += __shfl_xor(a4, 32, 64);
    m2 = fmaxf(m2, __shfl_xor(m2, 32, 64));
    c2_1 = (a4 > 0.f) ? (sqrtf(a2 / a4) * LOG2E) : 0.f;
    cm2_1 = c2_1 * m2;
  }

  // ---- PASS 2: fp16 scores -> w (in-register) -> PV; glds double-buffer ----
  f32x4 pv0[4], pv1[4];
#pragma unroll
  for (int dg = 0; dg < 4; ++dg) { pv0[dg] = fzero; pv1[dg] = fzero; }
  f32x4 denv0 = fzero, denv1 = fzero;

  for (int t = 0; t < 32; ++t) {
    __syncthreads();  // drains glds -> tile t ready
    if (t < 31) {
      int go = (t + 1) * 2048 + lds_o;
      int bs = (t + 1) & 1;
      GLDS16(kf_b + go, &k_t[bs][lds_o]);
      GLDS16(vt_b + go, &v_t[bs][lds_o]);
    }
    const f16_t* kt = k_t[t & 1];
    const f16_t* vl = v_t[t & 1];
    // V B-frags issued early (independent of score chain); shared by sets
    f16x8 vb[4];
#pragma unroll
    for (int dg = 0; dg < 4; ++dg)
      vb[dg] = *(const f16x8*)(vl + n * 32 + dg * 512 + g * 8);
    f16x8 b00 = *(const f16x8*)(kt + koff);
    f16x8 b01 = *(const f16x8*)(kt + (koff ^ 32));
    f16x8 b10 = *(const f16x8*)(kt + koff + 1024);
    f16x8 b11 = *(const f16x8*)(kt + (koff ^ 32) + 1024);
    // set0 scores
    f32x4 sc0_0 = MFMA16F(b00, qa0_0, fzero);
    sc0_0 = MFMA16F(b01, qa1_0, sc0_0);
    f32x4 sc1_0 = MFMA16F(b10, qa0_0, fzero);
    sc1_0 = MFMA16F(b11, qa1_0, sc1_0);
    // set1 scores
    f32x4 sc0_1 = MFMA16F(b00, qa0_1, fzero);
    sc0_1 = MFMA16F(b01, qa1_1, sc0_1);
    f32x4 sc1_1 = MFMA16F(b10, qa0_1, fzero);
    sc1_1 = MFMA16F(b11, qa1_1, sc1_1);
    // set0: w = 2^(c2*s^2 - c2*M) -> in-register A-frag
    f32x4 e0 = sc0_0 * sc0_0 * c2_0 - cm2_0;
    f32x4 e1 = sc1_0 * sc1_0 * c2_0 - cm2_0;
    f32x4 w0, w1;
#pragma unroll
    for (int r = 0; r < 4; ++r) { w0[r] = EXP2(e0[r]); w1[r] = EXP2(e1[r]); }
    denv0 += w0 + w1;
    unsigned X0 = pkh(w0[0], w0[1]), X1 = pkh(w0[2], w0[3]);
    unsigned Y0 = pkh(w1[0], w1[1]), Y1 = pkh(w1[2], w1[3]);
    pl32_swap(X0, Y0);
    pl16_swap(X0, Y0);
    pl32_swap(X1, Y1);
    pl16_swap(X1, Y1);
    u32x4 fu0 = {X0, X1, Y0, Y1};
    f16x8 wa0 = __builtin_bit_cast(f16x8, fu0);
    // set1
    f32x4 f0v = sc0_1 * sc0_1 * c2_1 - cm2_1;
    f32x4 f1v = sc1_1 * sc1_1 * c2_1 - cm2_1;
    f32x4 z0, z1;
#pragma unroll
    for (int r = 0; r < 4; ++r) { z0[r] = EXP2(f0v[r]); z1[r] = EXP2(f1v[r]); }
    denv1 += z0 + z1;
    unsigned P0 = pkh(z0[0], z0[1]), P1 = pkh(z0[2], z0[3]);
    unsigned Q0 = pkh(z1[0], z1[1]), Q1 = pkh(z1[2], z1[3]);
    pl32_swap(P0, Q0);
    pl16_swap(P0, Q0);
    pl32_swap(P1, Q1);
    pl16_swap(P1, Q1);
    u32x4 fu1 = {P0, P1, Q0, Q1};
    f16x8 wa1 = __builtin_bit_cast(f16x8, fu1);
#pragma unroll
    for (int dg = 0; dg < 4; ++dg) {
      pv0[dg] = MFMA16F(wa0, vb[dg], pv0[dg]);
      pv1[dg] = MFMA16F(wa1, vb[dg], pv1[dg]);
    }
  }

  // denominator: per-lane scalar -> cross-group reduce -> shfl to rows
  float den0 = (denv0[0] + denv0[1]) + (denv0[2] + denv0[3]);
  den0 += __shfl_xor(den0, 16, 64);
  den0 += __shfl_xor(den0, 32, 64);
  float den1 = (denv1[0] + denv1[1]) + (denv1[2] + denv1[3]);
  den1 += __shfl_xor(den1, 16, 64);
  den1 += __shfl_xor(den1, 32, 64);
#pragma unroll
  for (int r = 0; r < 4; ++r) {
    float dr0 = __shfl(den0, g * 4 + r, 64);
    float inv0 = 1.f / dr0;
    int l0 = qb * 128 + wave * 32 + g * 4 + r;
    float* op0 = out + (((size_t)b * L_ + l0) * H_ + h) * D_;
#pragma unroll
    for (int dg = 0; dg < 4; ++dg) op0[dg * 16 + n] = pv0[dg][r] * inv0;
    float dr1 = __shfl(den1, g * 4 + r, 64);
    float inv1 = 1.f / dr1;
    int l1 = l0 + 16;
    float* op1 = out + (((size_t)b * L_ + l1) * H_ + h) * D_;
#pragma unroll
    for (int dg = 0; dg < 4; ++dg) op1[dg * 16 + n] = pv1[dg][r] * inv1;
  }
}

extern "C" void kernel_launch(void* const* d_in, const int* in_sizes, int n_in,
                              void* d_out, int out_size, void* d_ws, size_t ws_size,
                              hipStream_t stream) {
  const float* q = (const float*)d_in[0];
  const float* k = (const float*)d_in[1];
  const float* v = (const float*)d_in[2];
  // d_in[3] (attn_mask) is all-False -> unused
  float* out = (float*)d_out;

  const size_t NE = (size_t)B_ * L_ * H_ * E_;  // 4,194,304 elems
  f16_t* qf = (f16_t*)d_ws;                     // ws usage: 3*NE*2B = 24 MB
  f16_t* kf = qf + NE;
  f16_t* vt = kf + NE;

  prep_kernel<<<8192 + 2048, 256, 0, stream>>>(q, k, v, qf, kf, vt);
  attn_kernel<<<BH_ * (L_ / 128), 256, 0, stream>>>(qf, kf, vt, out);
}

// Round 4
// 147.316 us; speedup vs baseline: 1.1363x; 1.0521x over previous
//
#include <hip/hip_runtime.h>
#include <hip/hip_bf16.h>

// FocusAttention: B=8, L=S=1024, H=8, E=D=64
// A = softmax(c * s^2) rowwise, c = sqrt(sum s^2 / sum s^4) (full-row const
// -> two passes over K; recompute QK^T in pass 2). out = A @ v, fp32.
//
// R10: R9 counters: occ 17.5% (grid 512 = 2 waves/SIMD), all pipes <25%
// utilized; per-CU accounting gives ~12us overlapped ideal vs 51us measured
// -> latency-bound, occupancy is the lever. 2-set waves must stay (LDS
// bytes/work), which caps total waves at 2048 = 8/CU... unless S is split.
// Fix: in-block S-split (flash-decoding style). 8 waves/block: waves 0-3 do
// s-tiles 0-15, waves 4-7 do s-tiles 16-31, same 128 q-rows. 16 waves/CU =
// 50% occ; L2/LDS/MFMA/VALU totals unchanged. Stats merged between passes
// (commutative -> bitwise-identical c2 in both partners); pv/den merged at
// the end via LDS. Also: V chunk XOR-swizzle (^=(d>>1)&3) kills the 1.05M
// V-read bank conflicts (K's pattern measured 0 in R8).
// Kept: swapped-operand QK^T, in-register w->A-frag (cvt_pkrtz + permlane),
// per-lane scalar stats/den, fp16, XCD swizzle, glds double-buffer, v_exp.

#define B_ 8
#define L_ 1024
#define H_ 8
#define E_ 64
#define S_ 1024
#define D_ 64
#define BH_ 64

typedef _Float16 f16_t;
typedef _Float16 f16x8 __attribute__((ext_vector_type(8)));
typedef _Float16 f16x4v __attribute__((ext_vector_type(4)));
typedef float f32x4 __attribute__((ext_vector_type(4)));
typedef unsigned u32x4 __attribute__((ext_vector_type(4)));

#define MFMA16F(a, b, c) __builtin_amdgcn_mfma_f32_16x16x32_f16(a, b, c, 0, 0, 0)
#define GLDS16(g, l)                                                        \
  __builtin_amdgcn_global_load_lds(                                         \
      (const __attribute__((address_space(1))) void*)(g),                   \
      (__attribute__((address_space(3))) void*)(l), 16, 0, 0)

#if __has_builtin(__builtin_amdgcn_exp2f)
#define EXP2(x) __builtin_amdgcn_exp2f(x)
#else
#define EXP2(x) exp2f(x)
#endif

// pack 2 f32 -> 1 dword of 2 f16 (v_cvt_pkrtz_f16_f32)
static __device__ __forceinline__ unsigned pkh(float a, float b) {
  return __builtin_bit_cast(unsigned, __builtin_amdgcn_cvt_pkrtz(a, b));
}

// v_permlane32_swap_b32: x[32:63] <-> y[0:31].
static __device__ __forceinline__ void pl32_swap(unsigned& x, unsigned& y) {
#if __has_builtin(__builtin_amdgcn_permlane32_swap)
  auto r = __builtin_amdgcn_permlane32_swap(x, y, false, false);
  x = r[0];
  y = r[1];
#else
  unsigned xs = __shfl_xor((int)x, 32, 64), ys = __shfl_xor((int)y, 32, 64);
  bool hi = (threadIdx.x & 32) != 0;
  unsigned nx = hi ? ys : x;
  unsigned ny = hi ? y : xs;
  x = nx;
  y = ny;
#endif
}

// v_permlane16_swap_b32: x rows {1,3} <-> y rows {0,2} (16-lane rows).
static __device__ __forceinline__ void pl16_swap(unsigned& x, unsigned& y) {
#if __has_builtin(__builtin_amdgcn_permlane16_swap)
  auto r = __builtin_amdgcn_permlane16_swap(x, y, false, false);
  x = r[0];
  y = r[1];
#else
  unsigned xs = __shfl_xor((int)x, 16, 64), ys = __shfl_xor((int)y, 16, 64);
  bool odd = (threadIdx.x & 16) != 0;
  unsigned nx = odd ? ys : x;
  unsigned ny = odd ? y : xs;
  x = nx;
  y = ny;
#endif
}

// ---------------------------------------------------------------------------
// prep: blocks [0,8192) = phi_p on q,k rows (4 rows/wave, float4 loads,
// f16x4 swizzled stores); blocks [8192,10240) = V transpose to
// vt[bh][st=S/32][64 d][32 s] f16, s-chunk XOR-swizzled by (d>>1)&3.
// Q/K XOR chunk swizzle: chunk c of row l stored at chunk c^(l&7).
// ---------------------------------------------------------------------------
__global__ __launch_bounds__(256) void prep_kernel(
    const float* __restrict__ q, const float* __restrict__ k,
    const float* __restrict__ v, f16_t* __restrict__ qf,
    f16_t* __restrict__ kf, f16_t* __restrict__ vt) {
  __shared__ float tile[32][68];
  int bid = blockIdx.x;
  if (bid < 8192) {
    int row = bid * 16 + (threadIdx.x >> 4);
    int p = threadIdx.x & 15;
    const float* src;
    f16_t* dst;
    int r = row;
    if (r < B_ * L_ * H_) { src = q; dst = qf; }
    else { r -= B_ * L_ * H_; src = k; dst = kf; }
    int b = r >> 13;            // r / (L*H)
    int l = (r >> 3) & 1023;
    int h = r & 7;
    float4 x = ((const float4*)(src + (size_t)r * 64))[p];
    float s0 = fmaxf(x.x, 0.f) * fmaxf(x.x, 0.f);
    float s1 = fmaxf(x.y, 0.f) * fmaxf(x.y, 0.f);
    float s2 = fmaxf(x.z, 0.f) * fmaxf(x.z, 0.f);
    float s3 = fmaxf(x.w, 0.f) * fmaxf(x.w, 0.f);
    float sum2 = (s0 + s1) + (s2 + s3);
    float sum4 = fmaf(s0, s0, s1 * s1) + fmaf(s2, s2, s3 * s3);
#pragma unroll
    for (int off = 1; off < 16; off <<= 1) {
      sum2 += __shfl_xor(sum2, off, 64);
      sum4 += __shfl_xor(sum4, off, 64);
    }
    float sc = (sum4 > 0.f) ? sqrtf(sum2 / sum4) : 0.f;
    f16x4v o = {(f16_t)(sc * s0), (f16_t)(sc * s1), (f16_t)(sc * s2),
                (f16_t)(sc * s3)};
    int c = p >> 1, e = (p & 1) * 4;
    int col = (((c ^ (l & 7)) << 3) | e);
    *(f16x4v*)(dst + ((size_t)(b * H_ + h) * 1024 + l) * 64 + col) = o;
  } else {
    int vb = bid - 8192;
    int bh = vb >> 5;
    int st = vb & 31;
    int b = bh >> 3, h = bh & 7;
    int t = threadIdx.x;
    int sl = t >> 3, dp = t & 7;
    const float* src =
        v + (((size_t)(b * S_ + st * 32 + sl) * H_ + h) * D_) + dp * 8;
    float4 f0 = ((const float4*)src)[0];
    float4 f1 = ((const float4*)src)[1];
    *(float4*)&tile[sl][dp * 8] = f0;
    *(float4*)&tile[sl][dp * 8 + 4] = f1;
    __syncthreads();
    int d = t >> 2, sc = t & 3;
    f16_t tmp[8];
#pragma unroll
    for (int j = 0; j < 8; ++j) tmp[j] = (f16_t)tile[sc * 8 + j][d];
    // s-chunk XOR swizzle by (d>>1)&3 -> conflict-free attn V reads
    f16_t* dst =
        vt + (((size_t)bh * 32 + st) * 64 + d) * 32 + (sc ^ ((d >> 1) & 3)) * 8;
    *(uint4*)dst = *(const uint4*)tmp;
  }
}

// ---------------------------------------------------------------------------
// K2: fused two-pass attention. Block = (b,h) x 128 q-rows, 512 threads =
// 8 waves. wave = (sh, wv): sh = s-half (tiles sh*16..sh*16+15), wv = row
// group (rows wv*32 + two 16-row sets). 16 waves/CU (grid 512, 2 blocks/CU).
// SWAPPED score MFMA: S^T = mfma(K_frag, Q_frag); lane(g,n) holds scores for
// q-row n. PV A-frag assembled in-register (cvt_pkrtz + permlane swaps).
// Stats merged across s-halves between passes; pv/den merged at the end.
// ---------------------------------------------------------------------------
__global__ __launch_bounds__(512, 4) void attn_kernel(
    const f16_t* __restrict__ qf, const f16_t* __restrict__ kf,
    const f16_t* __restrict__ vt, float* __restrict__ out) {
  __shared__ __align__(16) f16_t k_t[2][2][2048];  // [shalf][dbuf] 32s x 64e
  __shared__ __align__(16) f16_t v_t[2][2][2048];  // [shalf][dbuf] 64d x 32s
  __shared__ __align__(16) float mrg[4][64][34];   // final pv/den merge
  // (stats merge overlays mrg: needs 8*64*6 floats < 4*64*34)

  int bh = blockIdx.x & 63;   // XCD swizzle: all q-blocks of a head co-located
  int qb = blockIdx.x >> 6;   // 0..3 (128 rows each)
  int b = bh >> 3, h = bh & 7;
  int tid = threadIdx.x;
  int wave = tid >> 6, lane = tid & 63;
  int wv = wave & 3, sh = wave >> 2;
  int g = lane >> 4, n = lane & 15;

  const f16_t* qf_b = qf + ((size_t)bh * L_ + qb * 128) * 64;
  const f16_t* kf_b = kf + (size_t)bh * S_ * 64 + (size_t)sh * 16 * 2048;
  const f16_t* vt_b = vt + (size_t)bh * 32 * 2048 + (size_t)sh * 16 * 2048;

  // Q fragments, two sets (swizzled chunk addressing)
  int arow = wv * 32 + n;
  int qoff0 = arow * 64 + ((g ^ (n & 7)) << 3);
  int qoff1 = qoff0 + 16 * 64;
  f16x8 qa0_0 = *(const f16x8*)(qf_b + qoff0);
  f16x8 qa1_0 = *(const f16x8*)(qf_b + (qoff0 ^ 32));
  f16x8 qa0_1 = *(const f16x8*)(qf_b + qoff1);
  f16x8 qa1_1 = *(const f16x8*)(qf_b + (qoff1 ^ 32));

  // K fragment offset (row n; row n+16 at +1024); V frag offset (swizzled)
  int koff = n * 64 + ((g ^ (n & 7)) << 3);
  int voff = n * 32 + ((g ^ ((n >> 1) & 3)) << 3);
  int so = (tid & 255) * 8;  // lane-linear glds staging slot in own half

  const f32x4 fzero = {0.f, 0.f, 0.f, 0.f};
  f32x4 acc2_0 = fzero, acc4_0 = fzero, mx_0 = fzero;
  f32x4 acc2_1 = fzero, acc4_1 = fzero, mx_1 = fzero;

  // ---- PASS 1 (own s-half): row stats; K via glds double-buffer ----
  GLDS16(kf_b + so, &k_t[sh][0][so]);
  for (int t = 0; t < 16; ++t) {
    __syncthreads();  // drains glds -> tile t ready (both halves)
    if (t < 15)
      GLDS16(kf_b + (t + 1) * 2048 + so, &k_t[sh][(t + 1) & 1][so]);
    const f16_t* kt = k_t[sh][t & 1];
    f16x8 b00 = *(const f16x8*)(kt + koff);
    f16x8 b01 = *(const f16x8*)(kt + (koff ^ 32));
    f16x8 b10 = *(const f16x8*)(kt + koff + 1024);
    f16x8 b11 = *(const f16x8*)(kt + (koff ^ 32) + 1024);
    f32x4 sc0_0 = MFMA16F(b00, qa0_0, fzero);   // set0: S^T[s][q=n]
    sc0_0 = MFMA16F(b01, qa1_0, sc0_0);
    f32x4 sc1_0 = MFMA16F(b10, qa0_0, fzero);
    sc1_0 = MFMA16F(b11, qa1_0, sc1_0);
    f32x4 sc0_1 = MFMA16F(b00, qa0_1, fzero);   // set1: rows +16
    sc0_1 = MFMA16F(b01, qa1_1, sc0_1);
    f32x4 sc1_1 = MFMA16F(b10, qa0_1, fzero);
    sc1_1 = MFMA16F(b11, qa1_1, sc1_1);
    f32x4 t0 = sc0_0 * sc0_0, t1 = sc1_0 * sc1_0;
    acc2_0 += t0 + t1;
    acc4_0 += t0 * t0;
    acc4_0 += t1 * t1;
    mx_0 = __builtin_elementwise_max(mx_0, __builtin_elementwise_max(t0, t1));
    f32x4 u0 = sc0_1 * sc0_1, u1 = sc1_1 * sc1_1;
    acc2_1 += u0 + u1;
    acc4_1 += u0 * u0;
    acc4_1 += u1 * u1;
    mx_1 = __builtin_elementwise_max(mx_1, __builtin_elementwise_max(u0, u1));
  }
  // kick off pass-2 tile 0 staging; stats merge overlaps the load latency
  GLDS16(kf_b + so, &k_t[sh][0][so]);
  GLDS16(vt_b + so, &v_t[sh][0][so]);

  // in-wave reduce -> per-lane partial scalars (replicated over g)
  float a2_0 = (acc2_0[0] + acc2_0[1]) + (acc2_0[2] + acc2_0[3]);
  float a4_0 = (acc4_0[0] + acc4_0[1]) + (acc4_0[2] + acc4_0[3]);
  float m2_0 = fmaxf(fmaxf(mx_0[0], mx_0[1]), fmaxf(mx_0[2], mx_0[3]));
  float a2_1 = (acc2_1[0] + acc2_1[1]) + (acc2_1[2] + acc2_1[3]);
  float a4_1 = (acc4_1[0] + acc4_1[1]) + (acc4_1[2] + acc4_1[3]);
  float m2_1 = fmaxf(fmaxf(mx_1[0], mx_1[1]), fmaxf(mx_1[2], mx_1[3]));
  a2_0 += __shfl_xor(a2_0, 16, 64);
  a4_0 += __shfl_xor(a4_0, 16, 64);
  m2_0 = fmaxf(m2_0, __shfl_xor(m2_0, 16, 64));
  a2_1 += __shfl_xor(a2_1, 16, 64);
  a4_1 += __shfl_xor(a4_1, 16, 64);
  m2_1 = fmaxf(m2_1, __shfl_xor(m2_1, 16, 64));
  a2_0 += __shfl_xor(a2_0, 32, 64);
  a4_0 += __shfl_xor(a4_0, 32, 64);
  m2_0 = fmaxf(m2_0, __shfl_xor(m2_0, 32, 64));
  a2_1 += __shfl_xor(a2_1, 32, 64);
  a4_1 += __shfl_xor(a4_1, 32, 64);
  m2_1 = fmaxf(m2_1, __shfl_xor(m2_1, 32, 64));

  // cross-shalf stats merge (commutative adds/max -> bitwise-identical in
  // both partners)
  {
    float* sm = &mrg[0][0][0] + ((size_t)(wave * 64 + lane)) * 6;
    sm[0] = a2_0; sm[1] = a4_0; sm[2] = m2_0;
    sm[3] = a2_1; sm[4] = a4_1; sm[5] = m2_1;
  }
  __syncthreads();
  {
    const float* sp = &mrg[0][0][0] + ((size_t)((wave ^ 4) * 64 + lane)) * 6;
    a2_0 += sp[0]; a4_0 += sp[1]; m2_0 = fmaxf(m2_0, sp[2]);
    a2_1 += sp[3]; a4_1 += sp[4]; m2_1 = fmaxf(m2_1, sp[5]);
  }
  const float LOG2E = 1.44269504f;
  float c2_0 = (a4_0 > 0.f) ? (sqrtf(a2_0 / a4_0) * LOG2E) : 0.f;
  float cm2_0 = c2_0 * m2_0;
  float c2_1 = (a4_1 > 0.f) ? (sqrtf(a2_1 / a4_1) * LOG2E) : 0.f;
  float cm2_1 = c2_1 * m2_1;

  // ---- PASS 2 (own s-half): scores -> w (in-register) -> partial PV ----
  f32x4 pv0[4], pv1[4];
#pragma unroll
  for (int dg = 0; dg < 4; ++dg) { pv0[dg] = fzero; pv1[dg] = fzero; }
  f32x4 denv0 = fzero, denv1 = fzero;

  for (int t = 0; t < 16; ++t) {
    __syncthreads();  // drains glds -> tile t ready (both halves)
    if (t < 15) {
      int go = (t + 1) * 2048 + so;
      int bs = (t + 1) & 1;
      GLDS16(kf_b + go, &k_t[sh][bs][so]);
      GLDS16(vt_b + go, &v_t[sh][bs][so]);
    }
    const f16_t* kt = k_t[sh][t & 1];
    const f16_t* vl = v_t[sh][t & 1];
    // V B-frags issued early (independent of score chain); shared by sets
    f16x8 vb[4];
#pragma unroll
    for (int dg = 0; dg < 4; ++dg)
      vb[dg] = *(const f16x8*)(vl + voff + dg * 512);
    f16x8 b00 = *(const f16x8*)(kt + koff);
    f16x8 b01 = *(const f16x8*)(kt + (koff ^ 32));
    f16x8 b10 = *(const f16x8*)(kt + koff + 1024);
    f16x8 b11 = *(const f16x8*)(kt + (koff ^ 32) + 1024);
    // set0 scores
    f32x4 sc0_0 = MFMA16F(b00, qa0_0, fzero);
    sc0_0 = MFMA16F(b01, qa1_0, sc0_0);
    f32x4 sc1_0 = MFMA16F(b10, qa0_0, fzero);
    sc1_0 = MFMA16F(b11, qa1_0, sc1_0);
    // set1 scores
    f32x4 sc0_1 = MFMA16F(b00, qa0_1, fzero);
    sc0_1 = MFMA16F(b01, qa1_1, sc0_1);
    f32x4 sc1_1 = MFMA16F(b10, qa0_1, fzero);
    sc1_1 = MFMA16F(b11, qa1_1, sc1_1);
    // set0: w = 2^(c2*s^2 - c2*M) -> in-register A-frag
    f32x4 e0 = sc0_0 * sc0_0 * c2_0 - cm2_0;
    f32x4 e1 = sc1_0 * sc1_0 * c2_0 - cm2_0;
    f32x4 w0, w1;
#pragma unroll
    for (int r = 0; r < 4; ++r) { w0[r] = EXP2(e0[r]); w1[r] = EXP2(e1[r]); }
    denv0 += w0 + w1;
    unsigned X0 = pkh(w0[0], w0[1]), X1 = pkh(w0[2], w0[3]);
    unsigned Y0 = pkh(w1[0], w1[1]), Y1 = pkh(w1[2], w1[3]);
    pl32_swap(X0, Y0);
    pl16_swap(X0, Y0);
    pl32_swap(X1, Y1);
    pl16_swap(X1, Y1);
    u32x4 fu0 = {X0, X1, Y0, Y1};
    f16x8 wa0 = __builtin_bit_cast(f16x8, fu0);
    // set1
    f32x4 f0v = sc0_1 * sc0_1 * c2_1 - cm2_1;
    f32x4 f1v = sc1_1 * sc1_1 * c2_1 - cm2_1;
    f32x4 z0, z1;
#pragma unroll
    for (int r = 0; r < 4; ++r) { z0[r] = EXP2(f0v[r]); z1[r] = EXP2(f1v[r]); }
    denv1 += z0 + z1;
    unsigned P0 = pkh(z0[0], z0[1]), P1 = pkh(z0[2], z0[3]);
    unsigned Q0 = pkh(z1[0], z1[1]), Q1 = pkh(z1[2], z1[3]);
    pl32_swap(P0, Q0);
    pl16_swap(P0, Q0);
    pl32_swap(P1, Q1);
    pl16_swap(P1, Q1);
    u32x4 fu1 = {P0, P1, Q0, Q1};
    f16x8 wa1 = __builtin_bit_cast(f16x8, fu1);
#pragma unroll
    for (int dg = 0; dg < 4; ++dg) {
      pv0[dg] = MFMA16F(wa0, vb[dg], pv0[dg]);
      pv1[dg] = MFMA16F(wa1, vb[dg], pv1[dg]);
    }
  }

  // partial denominator -> per-lane scalar (replicated over g)
  float den0 = (denv0[0] + denv0[1]) + (denv0[2] + denv0[3]);
  den0 += __shfl_xor(den0, 16, 64);
  den0 += __shfl_xor(den0, 32, 64);
  float den1 = (denv1[0] + denv1[1]) + (denv1[2] + denv1[3]);
  den1 += __shfl_xor(den1, 16, 64);
  den1 += __shfl_xor(den1, 32, 64);

  // ---- cross-shalf pv/den merge; waves 0-3 normalize + store ----
  __syncthreads();  // all waves done with staging buffers & stats area
  if (sh == 1) {
    float* mp = &mrg[wv][lane][0];
#pragma unroll
    for (int dg = 0; dg < 4; ++dg)
#pragma unroll
      for (int r = 0; r < 4; ++r) {
        mp[dg * 4 + r] = pv0[dg][r];
        mp[16 + dg * 4 + r] = pv1[dg][r];
      }
    mp[32] = den0;
    mp[33] = den1;
  }
  __syncthreads();
  if (sh == 0) {
    const float* mp = &mrg[wv][lane][0];
#pragma unroll
    for (int dg = 0; dg < 4; ++dg)
#pragma unroll
      for (int r = 0; r < 4; ++r) {
        pv0[dg][r] += mp[dg * 4 + r];
        pv1[dg][r] += mp[16 + dg * 4 + r];
      }
    den0 += mp[32];
    den1 += mp[33];
#pragma unroll
    for (int r = 0; r < 4; ++r) {
      float dr0 = __shfl(den0, g * 4 + r, 64);
      float inv0 = 1.f / dr0;
      int l0 = qb * 128 + wv * 32 + g * 4 + r;
      float* op0 = out + (((size_t)b * L_ + l0) * H_ + h) * D_;
#pragma unroll
      for (int dg = 0; dg < 4; ++dg) op0[dg * 16 + n] = pv0[dg][r] * inv0;
      float dr1 = __shfl(den1, g * 4 + r, 64);
      float inv1 = 1.f / dr1;
      int l1 = l0 + 16;
      float* op1 = out + (((size_t)b * L_ + l1) * H_ + h) * D_;
#pragma unroll
      for (int dg = 0; dg < 4; ++dg) op1[dg * 16 + n] = pv1[dg][r] * inv1;
    }
  }
}

extern "C" void kernel_launch(void* const* d_in, const int* in_sizes, int n_in,
                              void* d_out, int out_size, void* d_ws, size_t ws_size,
                              hipStream_t stream) {
  const float* q = (const float*)d_in[0];
  const float* k = (const float*)d_in[1];
  const float* v = (const float*)d_in[2];
  // d_in[3] (attn_mask) is all-False -> unused
  float* out = (float*)d_out;

  const size_t NE = (size_t)B_ * L_ * H_ * E_;  // 4,194,304 elems
  f16_t* qf = (f16_t*)d_ws;                     // ws usage: 3*NE*2B = 24 MB
  f16_t* kf = qf + NE;
  f16_t* vt = kf + NE;

  prep_kernel<<<8192 + 2048, 256, 0, stream>>>(q, k, v, qf, kf, vt);
  attn_kernel<<<BH_ * (L_ / 128), 512, 0, stream>>>(qf, kf, vt, out);
}